// Round 9
// baseline (8487.744 us; speedup 1.0000x reference)
//
#include <hip/hip_runtime.h>
#include <hip/hip_bf16.h>
#include <stdint.h>

// ESN sizes (fixed by the reference)
#define NRR     4096
#define NBATCH  16
#define NFEAT   12
#define SEQLEN  1024
#define ALPHA_C 0.6f

typedef _Float16 f16x8 __attribute__((ext_vector_type(8)));
typedef _Float16 f16x2 __attribute__((ext_vector_type(2)));
typedef float    f32x4 __attribute__((ext_vector_type(4)));
typedef unsigned long long u64;

constexpr int WGS    = 256;            // 2 groups x 128 WGs
constexpr int TPB    = 512;            // 8 waves
constexpr int WAVES  = 8;
constexpr int GWGS   = 128;            // WGs per group
constexpr int BPG    = 8;              // batches per group (batch split!)
constexpr int ROWS   = 32;             // A-rows per WG (two 16-row MFMA tiles)
constexpr int KCHUNK = NRR / WAVES;    // 512 K per wave
constexpr int FRAGS  = KCHUNK / 32;    // 16 fragments per wave per step
constexpr int SLOTG  = BPG * NRR;      // fp16 elems per group r-slot (64 KB)

#define SC_AGENT __HIP_MEMORY_SCOPE_AGENT

__device__ __forceinline__ unsigned ld_rlx(const unsigned* p) {
    return __hip_atomic_load(p, __ATOMIC_RELAXED, SC_AGENT);
}
__device__ __forceinline__ u64 ld_rlx64(const void* p) {
    return __hip_atomic_load((const u64*)p, __ATOMIC_RELAXED, SC_AGENT);
}
__device__ __forceinline__ void st_rlx(unsigned* p, unsigned v) {
    __hip_atomic_store(p, v, __ATOMIC_RELAXED, SC_AGENT);
}
__device__ __forceinline__ void st_rlx_f32(float* p, float v) {
    __hip_atomic_store(p, v, __ATOMIC_RELAXED, SC_AGENT);
}

// Per-GROUP flat single-hop barrier (128 WGs). Two groups never sync with
// each other -> straggler domains decouple, poll footprint halves.
// 128 packed u32 slots per group = 64 u64 loads = ONE load per lane.
__device__ __forceinline__ void groupbar(unsigned* gslots, unsigned epoch,
                                         int gwg, int tid, int lane, int wave,
                                         int use_inv) {
    __syncthreads();   // drains each wave's vmcnt(0) -> sc1 stores at L3
    if (tid == 0) st_rlx(&gslots[gwg], epoch);
    if (wave == 0) {
        const u64* sp = (const u64*)gslots;  // 64 lanes x 2 slots = 128
        for (;;) {
            u64 v = ld_rlx64(&sp[lane]);
            bool ok = ((unsigned)v >= epoch) & ((unsigned)(v >> 32) >= epoch);
            if (__all(ok)) break;
        }
        // fallback (2-slot r ring): invalidate L1/L2 after all producers
        // committed, before any reused-address r-load
        if (use_inv && lane == 0)
            (void)__hip_atomic_load(&gslots[gwg], __ATOMIC_ACQUIRE, SC_AGENT);
    }
    __syncthreads();
    asm volatile("" ::: "memory");  // keep r-loads below the poll exit
}

// Fast tanh: clamp + single v_exp + rcp. |err| ~1e-6 << fp16 state quant.
__device__ __forceinline__ float fast_tanh(float v) {
    float vc = fminf(fmaxf(v, -10.0f), 10.0f);
    float e  = __expf(2.0f * vc);
    return (e - 1.0f) * __builtin_amdgcn_rcpf(e + 1.0f);
}

__global__ __launch_bounds__(TPB, 1) void esn_persistent(
    const float* __restrict__ x,    // (16, 1024, 12)
    const float* __restrict__ r0,   // (1, 16, 4096)
    const float* __restrict__ A,    // (4096, 4096) row-major
    const float* __restrict__ Bm,   // (4096, 12)
    const float* __restrict__ bias, // (4096,)
    const float* __restrict__ Cw,   // (8, 4096)
    float* __restrict__ out,        // (16, 8)
    unsigned* __restrict__ slots,   // 256 packed u32: [grp*128 + gwg]
    _Float16* __restrict__ rbuf,    // per-group r rings (streaming or 2-slot)
    float* __restrict__ rfin,       // (16, 4096) fp32 final state
    int use_inv)                    // 0 = streaming ring, 1 = 2-slot + INV
{
    const int wg    = blockIdx.x;
    const int grp   = wg >> 7;     // batch group 0/1 (batches 8g..8g+8)
    const int gwg   = wg & (GWGS - 1);
    const int tid   = threadIdx.x;
    const int wave  = tid >> 6;
    const int lane  = tid & 63;
    const int l15   = lane & 15;   // A row-in-tile / B batch col (0-7 live)
    const int g     = lane >> 4;   // k-group 0..3
    const int nbase = gwg * ROWS;  // this WG's 32 neuron rows

    unsigned* gslots = slots + grp * GWGS;
    _Float16* ring   = rbuf + (size_t)grp * (use_inv ? 2 : (SEQLEN + 1)) * SLOTG;

    __shared__ float lds_red[WAVES][BPG][ROWS];  // XOR-swizzled cols
    __shared__ float lds_x[2][BPG][NFEAT];
    __shared__ float lds_Bp[ROWS][NFEAT];
    __shared__ float lds_bias[ROWS];
    __shared__ float lds_out[4][128];

    // ---- A slice -> fp16 register fragments: two 16-row tiles, 128 VGPRs.
    // __launch_bounds__(512,1) => 2 waves/SIMD => 256-VGPR budget (no spill).
    uint4 afrag0[FRAGS], afrag1[FRAGS];
#pragma unroll
    for (int tt = 0; tt < 2; ++tt) {
        const float* arow = A + (size_t)(nbase + tt * 16 + l15) * NRR + wave * KCHUNK + g * 8;
#pragma unroll
        for (int i = 0; i < FRAGS; ++i) {
            const float4* p = (const float4*)(arow + i * 32);
            float4 f0 = p[0];
            float4 f1 = p[1];
            f16x8 h;
            h[0] = (_Float16)f0.x; h[1] = (_Float16)f0.y;
            h[2] = (_Float16)f0.z; h[3] = (_Float16)f0.w;
            h[4] = (_Float16)f1.x; h[5] = (_Float16)f1.y;
            h[6] = (_Float16)f1.z; h[7] = (_Float16)f1.w;
            (tt == 0 ? afrag0 : afrag1)[i] = __builtin_bit_cast(uint4, h);
        }
    }

    // x prefetch mapping (tid<96): thread owns (group-batch xb, feat xf)
    const int xb = tid / NFEAT;           // 0..7 for tid<96
    const int xf = tid % NFEAT;
    const size_t xofs = (size_t)(grp * BPG + xb) * SEQLEN * NFEAT + xf;

    if (tid < ROWS * NFEAT)
        lds_Bp[tid / NFEAT][tid % NFEAT] = Bm[(size_t)(nbase + tid / NFEAT) * NFEAT + tid % NFEAT];
    if (tid < ROWS)
        lds_bias[tid] = bias[nbase + tid];
    if (tid < BPG * NFEAT)
        lds_x[0][xb][xf] = x[xofs];  // x[:, 0, :]

    // ---- master fp32 state: tid<256 owns (batch = grp*8 + (tid>>5), row = tid&31)
    const int ub = tid >> 5;   // group-batch 0..7
    const int un = tid & 31;   // row 0..31
    float rm = 0.0f;
    if (tid < 256) {
        rm = r0[(grp * BPG + ub) * NRR + nbase + un];
        float hi = __shfl_down(rm, 1);
        if (!(un & 1)) {
            f16x2 h2; h2[0] = (_Float16)rm; h2[1] = (_Float16)hi;
            st_rlx((unsigned*)(ring + (size_t)ub * NRR + nbase + un),
                   __builtin_bit_cast(unsigned, h2));
        }
    }

    groupbar(gslots, 1u, gwg, tid, lane, wave, use_inv);

    const size_t roff = (size_t)(l15 & 7) * NRR + wave * KCHUNK + g * 8;
    const int    swz  = (l15 & 3) << 2;   // store-side XOR key (within 16-col tile)
    const int    rsw  = ((un & 15) ^ ((ub & 3) << 2)) | (un & 16);  // read col

    for (int t = 0; t < SEQLEN; ++t) {
        const _Float16* rcur = ring + (size_t)(use_inv ? (t & 1) : t) * SLOTG;
        _Float16*       rnxt = ring + (size_t)(use_inv ? ((t + 1) & 1) : (t + 1)) * SLOTG;

        // kick x[t+1] prefetch
        float xp = 0.0f;
        if (tid < BPG * NFEAT && t + 1 < SEQLEN)
            xp = x[xofs + (size_t)(t + 1) * NFEAT];

        // S[n,b] partials; r via PLAIN cached uint4 (fresh ring slot).
        // Only lanes l15<8 carry live B columns (8 batches); others zero.
        f32x4 acc0 = {0.f, 0.f, 0.f, 0.f};
        f32x4 acc1 = {0.f, 0.f, 0.f, 0.f};
        const _Float16* rrow = rcur + roff;
#pragma unroll
        for (int i = 0; i < FRAGS; ++i) {
            uint4 u = {0u, 0u, 0u, 0u};
            if (l15 < 8) u = *(const uint4*)(rrow + i * 32);
            f16x8 rv = __builtin_bit_cast(f16x8, u);
            acc0 = __builtin_amdgcn_mfma_f32_16x16x32_f16(
                __builtin_bit_cast(f16x8, afrag0[i]), rv, acc0, 0, 0, 0);
            acc1 = __builtin_amdgcn_mfma_f32_16x16x32_f16(
                __builtin_bit_cast(f16x8, afrag1[i]), rv, acc1, 0, 0, 0);
        }
        // D layout: col=lane&15 (batch), row=(lane>>4)*4+j. Store both tiles
        // XOR-swizzled -> conflict-free (2-way) f32x4 ds_writes.
        if (l15 < 8) {
            *(f32x4*)&lds_red[wave][l15][(g * 4) ^ swz]      = acc0;
            *(f32x4*)&lds_red[wave][l15][16 + ((g * 4) ^ swz)] = acc1;
        }
        __syncthreads();

        if (tid < 256) {
            float s = 0.f;
#pragma unroll
            for (int w = 0; w < WAVES; ++w) s += lds_red[w][ub][rsw];
            float p = lds_bias[un];
            const float* xr = lds_x[t & 1][ub];
#pragma unroll
            for (int f = 0; f < NFEAT; ++f) p += lds_Bp[un][f] * xr[f];
            rm = (1.0f - ALPHA_C) * rm + ALPHA_C * fast_tanh(s + p);
            float hi = __shfl_down(rm, 1);
            if (!(un & 1)) {
                f16x2 h2; h2[0] = (_Float16)rm; h2[1] = (_Float16)hi;
                st_rlx((unsigned*)(rnxt + (size_t)ub * NRR + nbase + un),
                       __builtin_bit_cast(unsigned, h2));
            }
            if (t == SEQLEN - 1)
                st_rlx_f32(&rfin[(size_t)(grp * BPG + ub) * NRR + nbase + un], rm);
        }
        if (tid < BPG * NFEAT && t + 1 < SEQLEN)
            lds_x[(t + 1) & 1][xb][xf] = xp;

        groupbar(gslots, (unsigned)(t + 2), gwg, tid, lane, wave, use_inv);
    }

    // ---- readout: out[b,o] = sum_k rfin[b,k] * Cw[o,k], by global WG 0 ----
    if (wg == 0) {
        // wait for BOTH groups' final publish (epoch SEQLEN+1) across all 256 slots
        if (wave == 0) {
            const u64* sp = (const u64*)slots;
            const unsigned fin = SEQLEN + 1u;
            for (;;) {
                u64 a = ld_rlx64(&sp[lane]);
                u64 b = ld_rlx64(&sp[64 + lane]);
                bool ok = ((unsigned)a >= fin) & ((unsigned)(a >> 32) >= fin) &
                          ((unsigned)b >= fin) & ((unsigned)(b >> 32) >= fin);
                if (__all(ok)) break;
            }
        }
        __syncthreads();
        const int oi   = tid & 127;  // = b*8 + o
        const int part = tid >> 7;   // K-quarter
        const int b = oi >> 3, o = oi & 7;
        const float* rv = rfin + (size_t)b * NRR + part * (NRR / 4);
        const float* cv = Cw   + (size_t)o * NRR + part * (NRR / 4);
        float s = 0.f;
        for (int k = 0; k < NRR / 4; k += 2) {
            u64 u = ld_rlx64(rv + k);
            float ra = __builtin_bit_cast(float, (unsigned)u);
            float rb = __builtin_bit_cast(float, (unsigned)(u >> 32));
            s += ra * cv[k] + rb * cv[k + 1];
        }
        lds_out[part][oi] = s;
        __syncthreads();
        if (tid < 128)
            out[tid] = lds_out[0][tid] + lds_out[1][tid] + lds_out[2][tid] + lds_out[3][tid];
    }
}

extern "C" void kernel_launch(void* const* d_in, const int* in_sizes, int n_in,
                              void* d_out, int out_size, void* d_ws, size_t ws_size,
                              hipStream_t stream) {
    const float* x   = (const float*)d_in[0];
    const float* r0  = (const float*)d_in[1];
    const float* A   = (const float*)d_in[2];
    const float* Bm  = (const float*)d_in[3];
    const float* bv  = (const float*)d_in[4];
    const float* Cw  = (const float*)d_in[5];
    float*       out = (float*)d_out;

    char* ws = (char*)d_ws;
    unsigned*  slots = (unsigned*)ws;                       // 1 KB (256 packed u32)
    float*     rfin  = (float*)(ws + 4096);                 // 256 KB
    _Float16*  rbuf  = (_Float16*)(ws + 4096 + 262144);     // per-group r rings

    // Streaming rings: 2 groups x (SEQLEN+1) x 64 KB = ~134.4 MB.
    const size_t need_stream = 4096 + 262144 + 2 * (size_t)(SEQLEN + 1) * SLOTG * 2;
    int use_inv = (ws_size >= need_stream) ? 0 : 1;

    // slots must start at 0 every call (incl. graph replays)
    hipMemsetAsync(ws, 0, 4096, stream);

    void* args[] = {(void*)&x, (void*)&r0, (void*)&A, (void*)&Bm, (void*)&bv, (void*)&Cw,
                    (void*)&out, (void*)&slots, (void*)&rbuf, (void*)&rfin,
                    (void*)&use_inv};
    hipError_t e = hipLaunchCooperativeKernel((const void*)esn_persistent,
                                              dim3(WGS), dim3(TPB), args, 0, stream);
    if (e != hipSuccess) {
        hipLaunchKernelGGL(esn_persistent, dim3(WGS), dim3(TPB), 0, stream,
                           x, r0, A, Bm, bv, Cw, out, slots, rbuf, rfin, use_inv);
    }
}